// Round 17
// baseline (306.648 us; speedup 1.0000x reference)
//
#include <hip/hip_runtime.h>
#include <math.h>

#define E_ 8
#define H_ 256
#define N_ 65536
#define NHID_ 3
#define MT 64          // points per tile; block handles 2 tiles (A,B) = 128 points
#define HPAD 264       // LDS row stride (bf16 elems): row stride 528B
#define OMEGA_ 30.0f
#define REV_SCALE 4.7746482927568605f   // OMEGA/(2*pi): sin(OMEGA*z) = sin(2pi*(REV_SCALE*z))

// ws layout: Pwh_hi | Pwh_lo | Pwo_hi | Pwo_lo (lo planes used only by output layer / fallback)
#define PWH_ELEMS (E_ * NHID_ * 8 * 16 * 64 * 8)   // 1572864 bf16 = 3145728 B
#define PWO_ELEMS (E_ * 8 * 64 * 8)                // 32768 bf16 = 65536 B
#define WS_NEEDED (2 * (size_t)PWH_ELEMS * 2 + 2 * (size_t)PWO_ELEMS * 2)  // 6422528 B

typedef __attribute__((ext_vector_type(8))) __bf16 bf16x8;
typedef __attribute__((ext_vector_type(4))) float f32x4;

// RNE split (pack kernels + fallback path)
__device__ __forceinline__ void split_bf16(float v, __bf16& hi, __bf16& lo) {
  hi = (__bf16)v;
  lo = (__bf16)(v - (float)hi);
}

// hot-path: sin + RNE-bf16 + single LDS store
__device__ __forceinline__ void sin_store(float z_rev, __bf16* h, int idx) {
  const float s = __builtin_amdgcn_sinf(__builtin_amdgcn_fractf(z_rev)); // sin(2*pi*z_rev)
  h[idx] = (__bf16)s;   // RNE
}

// ---- zero d_out ----
__global__ void zero_out_k(float* __restrict__ out) {
  out[blockIdx.x * 256 + threadIdx.x] = 0.0f;   // grid exactly N_*3/256
}

// ---- pack Wh*REV_SCALE -> bf16 hi/lo B-fragment order (16x16x32) ----
// value(t,j) = REV_SCALE * Wh[el][kb*32+quad*8+j][nb*16+l15]
// threads = 8*3*8*16*64 = 196608 -> grid 768 x 256
__global__ void pack_wh_k(const float* __restrict__ Wh,
                          __bf16* __restrict__ Phi, __bf16* __restrict__ Plo) {
  int t = blockIdx.x * 256 + threadIdx.x;
  int lane = t & 63;
  int r = t >> 6;            // [0, 3072)
  int nb = r & 15;
  int kb = (r >> 4) & 7;
  int el = r >> 7;           // [0, 24) = e*3+l
  int n  = nb * 16 + (lane & 15);
  int k0 = kb * 32 + (lane >> 4) * 8;
  const float* src = Wh + (size_t)el * (H_ * H_);
  __bf16* dhi = Phi + (size_t)t * 8;
  __bf16* dlo = Plo + (size_t)t * 8;
#pragma unroll
  for (int j = 0; j < 8; ++j) {
    __bf16 hi, lo;
    split_bf16(src[(size_t)(k0 + j) * H_ + n] * REV_SCALE, hi, lo);
    dhi[j] = hi; dlo[j] = lo;
  }
}

// ---- pack Wout (UNscaled — final layer is linear), 16x16x32 layout ----
__global__ void pack_wout_k(const float* __restrict__ Wout,
                            __bf16* __restrict__ Phi, __bf16* __restrict__ Plo) {
  int t = blockIdx.x * 256 + threadIdx.x;   // 4096 threads -> grid 16 x 256
  int lane = t & 63;
  int kb = (t >> 6) & 7;
  int e  = t >> 9;
  int n  = lane & 15;
  int k0 = kb * 32 + (lane >> 4) * 8;
  __bf16* dhi = Phi + (size_t)t * 8;
  __bf16* dlo = Plo + (size_t)t * 8;
#pragma unroll
  for (int j = 0; j < 8; ++j) {
    float v = (n < 3) ? Wout[((size_t)e * H_ + (k0 + j)) * 3 + n] : 0.0f;
    __bf16 hi, lo;
    split_bf16(v, hi, lo);
    dhi[j] = hi; dlo[j] = lo;
  }
}

// bias-folded accumulator init (C/D col = lane-only; one bias per nbi, all 16 regs)
__device__ __forceinline__ void init_acc_bias(f32x4 (&acc)[4][4],
                                              const float* __restrict__ bhrow,
                                              int nb0, int l15) {
  float br[4];
#pragma unroll
  for (int nbi = 0; nbi < 4; ++nbi)
    br[nbi] = bhrow[(nb0 + nbi) * 16 + l15] * REV_SCALE;
#pragma unroll
  for (int mt = 0; mt < 4; ++mt)
#pragma unroll
    for (int nbi = 0; nbi < 4; ++nbi)
      acc[mt][nbi] = (f32x4){br[nbi], br[nbi], br[nbi], br[nbi]};
}

// ---- fused segment: K-loop of tile hK (MFMA) interleaved with a VALU phase ----
// MODE 0: drain accE (previous layer's acc, bias pre-folded) -> sin -> hE.
//   Chunk c drains values mt=c>>1, nbi=(c&1)*2+(j>>2), i=j&3 (all compile-time).
// MODE 1: first-sine-layer rows c*8+j of tile E -> hE (x loads wave-uniform).
// Intra-wave MFMA/VALU interleave: MFMA occupies the matrix pipe ~5cyc but the
// issue slot ~1cyc; the fused stream fills the gap with sin/cvt/ds_write.
template<int MODE>
__device__ __forceinline__ void fused_K_seg(
    const __bf16* __restrict__ pBh,
    const __bf16* __restrict__ hK,
    f32x4 (&accK)[4][4],
    f32x4 (&accE)[4][4],
    __bf16* __restrict__ hE,
    const float* __restrict__ x, int m0E,
    float w0, float w1, float bb,
    int tid, int l15, int quad, int nb0)
{
#pragma unroll
  for (int c = 0; c < 8; ++c) {
    bf16x8 bhf[4];
#pragma unroll
    for (int nbi = 0; nbi < 4; ++nbi)
      bhf[nbi] = *reinterpret_cast<const bf16x8*>(pBh + c * 8192 + nbi * 512);
    const int k0 = c * 32 + quad * 8;
    bf16x8 ah[4];
#pragma unroll
    for (int mt = 0; mt < 4; ++mt)
      ah[mt] = *reinterpret_cast<const bf16x8*>(&hK[(mt * 16 + l15) * HPAD + k0]);
#pragma unroll
    for (int mt = 0; mt < 4; ++mt)
#pragma unroll
      for (int nbi = 0; nbi < 4; ++nbi)
        accK[mt][nbi] = __builtin_amdgcn_mfma_f32_16x16x32_bf16(
            ah[mt], bhf[nbi], accK[mt][nbi], 0, 0, 0);
    if (MODE == 0) {
#pragma unroll
      for (int j = 0; j < 8; ++j) {
        const int mt  = c >> 1;
        const int nbi = (c & 1) * 2 + (j >> 2);
        const int i   = j & 3;
        sin_store(accE[mt][nbi][i], hE,
                  (mt * 16 + quad * 4 + i) * HPAD + (nb0 + nbi) * 16 + l15);
      }
    } else {
#pragma unroll
      for (int j = 0; j < 8; ++j) {
        const int r = c * 8 + j;
        const float xx0 = x[(m0E + r) * 2 + 0];
        const float xx1 = x[(m0E + r) * 2 + 1];
        sin_store(fmaf(xx1, w1, fmaf(xx0, w0, bb)), hE, r * HPAD + tid);
      }
    }
  }
}

// ---- fused output-layer segment: out-MFMA of hK + drain accE -> hE ----
__device__ __forceinline__ void fused_out_seg(
    const __bf16* __restrict__ pOh, const __bf16* __restrict__ pOl,
    const __bf16* __restrict__ hK, f32x4& accO,
    f32x4 (&accE)[4][4], __bf16* __restrict__ hE,
    int wave, int l15, int quad, int nb0)
{
  const int arow = wave * 16 + l15;
#pragma unroll
  for (int c = 0; c < 8; ++c) {
    bf16x8 bhf = *reinterpret_cast<const bf16x8*>(pOh + c * 512);
    bf16x8 blf = *reinterpret_cast<const bf16x8*>(pOl + c * 512);
    bf16x8 ah  = *reinterpret_cast<const bf16x8*>(&hK[arow * HPAD + c * 32 + quad * 8]);
    accO = __builtin_amdgcn_mfma_f32_16x16x32_bf16(ah, blf, accO, 0, 0, 0);
    accO = __builtin_amdgcn_mfma_f32_16x16x32_bf16(ah, bhf, accO, 0, 0, 0);
#pragma unroll
    for (int j = 0; j < 8; ++j) {
      const int mt  = c >> 1;
      const int nbi = (c & 1) * 2 + (j >> 2);
      const int i   = j & 3;
      sin_store(accE[mt][nbi][i], hE,
                (mt * 16 + quad * 4 + i) * HPAD + (nb0 + nbi) * 16 + l15);
    }
  }
}

// ---- fused MoE-SIREN, 2-tile ping-pong (R17) ----
// R16 counters: dur = MFMA work (99us) + VALU work (120us) exactly — zero pipe
// overlap; cross-wave drift/stagger refuted (R14-R16). This kernel fuses the
// phases INTRA-wave: block owns tiles A,B; each segment runs X's K-loop (MFMA)
// source-interleaved with Y's epilogue (VALU). 9 barriers; accA+accB = 128 AGPR
// at 2 waves/SIMD (LDS 68KB -> 2 blocks/CU). Floor if overlap works:
// max(120,99)+edges ~ 150-190us.
__global__ __launch_bounds__(256, 2) void moe_main_packed_k(
    const float* __restrict__ x,
    const float* __restrict__ gate_W,
    const float* __restrict__ gate_b,
    const float* __restrict__ W0,
    const float* __restrict__ b0,
    const __bf16* __restrict__ Pwh_hi,
    const __bf16* __restrict__ Pwh_lo,
    const float* __restrict__ bh,
    const __bf16* __restrict__ Pwo_hi,
    const __bf16* __restrict__ Pwo_lo,
    const float* __restrict__ bout,
    float* __restrict__ out)
{
  __shared__ alignas(16) __bf16 hA[MT * HPAD];   // 33792 B
  __shared__ alignas(16) __bf16 hB[MT * HPAD];   // 33792 B
  __shared__ float gate_s[2 * MT];               // total ~68.1 KB -> 2 blocks/CU

  const int e    = blockIdx.y;
  const int m0   = blockIdx.x * (2 * MT);        // tile A = m0, tile B = m0+MT
  const int tid  = threadIdx.x;
  const int wave = tid >> 6;
  const int lane = tid & 63;
  const int l15  = lane & 15;
  const int quad = lane >> 4;
  const int nb0  = wave * 4;

  // gate for both tiles (128 points), one per thread
  if (tid < 2 * MT) {
    const int mg = m0 + tid;
    const float x0 = x[mg * 2 + 0];
    const float x1 = x[mg * 2 + 1];
    float lg[E_];
    float mx = -1e30f;
#pragma unroll
    for (int k = 0; k < E_; ++k) {
      lg[k] = x0 * gate_W[k] + x1 * gate_W[E_ + k] + gate_b[k];
      mx = fmaxf(mx, lg[k]);
    }
    float s = 0.0f;
#pragma unroll
    for (int k = 0; k < E_; ++k) s += __expf(lg[k] - mx);
    gate_s[tid] = __expf(lg[e] - mx) / s;
  }

  // first-layer weights for column tid (shared by tiles A and B)
  const float w0a = W0[(e * 2 + 0) * H_ + tid] * REV_SCALE;
  const float w1a = W0[(e * 2 + 1) * H_ + tid] * REV_SCALE;
  const float bba = b0[e * H_ + tid] * REV_SCALE;

  // pre: first sine layer, tile A (plain)
  for (int m = 0; m < MT; ++m) {
    const float x0 = x[(m0 + m) * 2 + 0];
    const float x1 = x[(m0 + m) * 2 + 1];
    sin_store(fmaf(x1, w1a, fmaf(x0, w0a, bba)), hA, m * HPAD + tid);
  }
  __syncthreads();

  const size_t fragoff = (size_t)(nb0 * 64 + lane) * 8;
  const float* bh_e = bh + (size_t)(e * NHID_) * H_;
  const __bf16* PB0 = Pwh_hi + (size_t)(e * NHID_ + 0) * (8 * 16 * 64 * 8) + fragoff;
  const __bf16* PB1 = Pwh_hi + (size_t)(e * NHID_ + 1) * (8 * 16 * 64 * 8) + fragoff;
  const __bf16* PB2 = Pwh_hi + (size_t)(e * NHID_ + 2) * (8 * 16 * 64 * 8) + fragoff;

  f32x4 accA[4][4], accB[4][4];

  // s0: K0(A) + first(B)
  init_acc_bias(accA, bh_e + 0 * H_, nb0, l15);
  fused_K_seg<1>(PB0, hA, accA, accA, hB, x, m0 + MT, w0a, w1a, bba, tid, l15, quad, nb0);
  __syncthreads();

  // s1: K0(B) + epi0(A)
  init_acc_bias(accB, bh_e + 0 * H_, nb0, l15);
  fused_K_seg<0>(PB0, hB, accB, accA, hA, x, 0, 0.f, 0.f, 0.f, tid, l15, quad, nb0);
  __syncthreads();

  // s2: K1(A) + epi0(B)
  init_acc_bias(accA, bh_e + 1 * H_, nb0, l15);
  fused_K_seg<0>(PB1, hA, accA, accB, hB, x, 0, 0.f, 0.f, 0.f, tid, l15, quad, nb0);
  __syncthreads();

  // s3: K1(B) + epi1(A)
  init_acc_bias(accB, bh_e + 1 * H_, nb0, l15);
  fused_K_seg<0>(PB1, hB, accB, accA, hA, x, 0, 0.f, 0.f, 0.f, tid, l15, quad, nb0);
  __syncthreads();

  // s4: K2(A) + epi1(B)
  init_acc_bias(accA, bh_e + 2 * H_, nb0, l15);
  fused_K_seg<0>(PB2, hA, accA, accB, hB, x, 0, 0.f, 0.f, 0.f, tid, l15, quad, nb0);
  __syncthreads();

  // s5: K2(B) + epi2(A)
  init_acc_bias(accB, bh_e + 2 * H_, nb0, l15);
  fused_K_seg<0>(PB2, hB, accB, accA, hA, x, 0, 0.f, 0.f, 0.f, tid, l15, quad, nb0);
  __syncthreads();

  // s6: out(A) + epi2(B)
  const __bf16* pOh = Pwo_hi + (size_t)e * (8 * 64 * 8) + (size_t)lane * 8;
  const __bf16* pOl = Pwo_lo + (size_t)e * (8 * 64 * 8) + (size_t)lane * 8;
  {
    f32x4 accO = (f32x4){0.f, 0.f, 0.f, 0.f};
    fused_out_seg(pOh, pOl, hA, accO, accB, hB, wave, l15, quad, nb0);
    if (l15 < 3) {
      const float bo = bout[e * 3 + l15];
      const int rb = wave * 16 + quad * 4;
#pragma unroll
      for (int i = 0; i < 4; ++i) {
        const int m = rb + i;
        atomicAdd(&out[(size_t)(m0 + m) * 3 + l15], gate_s[m] * (accO[i] + bo));
      }
    }
  }
  __syncthreads();

  // s7: out(B) plain
  {
    f32x4 accO = (f32x4){0.f, 0.f, 0.f, 0.f};
    const int arow = wave * 16 + l15;
#pragma unroll
    for (int c = 0; c < 8; ++c) {
      bf16x8 bhf = *reinterpret_cast<const bf16x8*>(pOh + c * 512);
      bf16x8 blf = *reinterpret_cast<const bf16x8*>(pOl + c * 512);
      bf16x8 ah  = *reinterpret_cast<const bf16x8*>(&hB[arow * HPAD + c * 32 + quad * 8]);
      accO = __builtin_amdgcn_mfma_f32_16x16x32_bf16(ah, blf, accO, 0, 0, 0);
      accO = __builtin_amdgcn_mfma_f32_16x16x32_bf16(ah, bhf, accO, 0, 0, 0);
    }
    if (l15 < 3) {
      const float bo = bout[e * 3 + l15];
      const int rb = wave * 16 + quad * 4;
#pragma unroll
      for (int i = 0; i < 4; ++i) {
        const int m = rb + i;
        atomicAdd(&out[(size_t)(m0 + MT + m) * 3 + l15], gate_s[MT + m] * (accO[i] + bo));
      }
    }
  }
}

// ---- fallback: direct fp32-weight path (HW-verified round 3, MT=64, 3-term) ----
__global__ __launch_bounds__(256) void moe_main_direct_k(
    const float* __restrict__ x,
    const float* __restrict__ gate_W,
    const float* __restrict__ gate_b,
    const float* __restrict__ W0,
    const float* __restrict__ b0,
    const float* __restrict__ Wh,
    const float* __restrict__ bh,
    const float* __restrict__ Wout,
    const float* __restrict__ bout,
    float* __restrict__ out)
{
  __shared__ alignas(16) __bf16 h_hi[MT * HPAD];
  __shared__ alignas(16) __bf16 h_lo[MT * HPAD];
  __shared__ float gate_s[MT];

  const int e    = blockIdx.y;
  const int m0   = blockIdx.x * MT;
  const int tid  = threadIdx.x;
  const int wave = tid >> 6;
  const int lane = tid & 63;
  const int l15  = lane & 15;
  const int quad = lane >> 4;

  if (tid < MT) {
    const int mg = m0 + tid;
    const float x0 = x[mg * 2 + 0];
    const float x1 = x[mg * 2 + 1];
    float lg[E_];
    float mx = -1e30f;
#pragma unroll
    for (int k = 0; k < E_; ++k) {
      lg[k] = x0 * gate_W[k] + x1 * gate_W[E_ + k] + gate_b[k];
      mx = fmaxf(mx, lg[k]);
    }
    float s = 0.0f;
#pragma unroll
    for (int k = 0; k < E_; ++k) s += __expf(lg[k] - mx);
    gate_s[tid] = __expf(lg[e] - mx) / s;
  }
  {
    const float w0a = W0[(e * 2 + 0) * H_ + tid];
    const float w1a = W0[(e * 2 + 1) * H_ + tid];
    const float bb  = b0[e * H_ + tid];
    for (int m = 0; m < MT; ++m) {
      const float x0 = x[(m0 + m) * 2 + 0];
      const float x1 = x[(m0 + m) * 2 + 1];
      const float z = OMEGA_ * fmaf(x1, w1a, fmaf(x0, w0a, bb));
      const float h = __sinf(z);
      __bf16 hi, lo; split_bf16(h, hi, lo);
      h_hi[m * HPAD + tid] = hi;
      h_lo[m * HPAD + tid] = lo;
    }
  }
  __syncthreads();

  const int nb0 = wave * 4;
#pragma unroll 1
  for (int l = 0; l < NHID_; ++l) {
    const float* WB = Wh + (size_t)(e * NHID_ + l) * (H_ * H_);
    f32x4 acc[4][4];
#pragma unroll
    for (int mt = 0; mt < 4; ++mt)
#pragma unroll
      for (int nbi = 0; nbi < 4; ++nbi)
        acc[mt][nbi] = (f32x4){0.f, 0.f, 0.f, 0.f};

#pragma unroll 2
    for (int kb = 0; kb < 8; ++kb) {
      const int k0 = kb * 32 + quad * 8;
      float bfv[4][8];
#pragma unroll
      for (int nbi = 0; nbi < 4; ++nbi) {
        const float* p = WB + (size_t)k0 * H_ + (nb0 + nbi) * 16 + l15;
#pragma unroll
        for (int j = 0; j < 8; ++j) bfv[nbi][j] = p[(size_t)j * H_];
      }
      bf16x8 ah[4], al[4];
#pragma unroll
      for (int mt = 0; mt < 4; ++mt) {
        ah[mt] = *reinterpret_cast<const bf16x8*>(&h_hi[(mt * 16 + l15) * HPAD + k0]);
        al[mt] = *reinterpret_cast<const bf16x8*>(&h_lo[(mt * 16 + l15) * HPAD + k0]);
      }
      bf16x8 bhf[4], blf[4];
#pragma unroll
      for (int nbi = 0; nbi < 4; ++nbi)
#pragma unroll
        for (int j = 0; j < 8; ++j) {
          __bf16 hi, lo; split_bf16(bfv[nbi][j], hi, lo);
          bhf[nbi][j] = hi; blf[nbi][j] = lo;
        }
#pragma unroll
      for (int mt = 0; mt < 4; ++mt)
#pragma unroll
        for (int nbi = 0; nbi < 4; ++nbi) {
          f32x4 a = acc[mt][nbi];
          a = __builtin_amdgcn_mfma_f32_16x16x32_bf16(al[mt], bhf[nbi], a, 0, 0, 0);
          a = __builtin_amdgcn_mfma_f32_16x16x32_bf16(ah[mt], blf[nbi], a, 0, 0, 0);
          a = __builtin_amdgcn_mfma_f32_16x16x32_bf16(ah[mt], bhf[nbi], a, 0, 0, 0);
          acc[mt][nbi] = a;
        }
    }
    __syncthreads();

    const float* bhrow = bh + (size_t)(e * NHID_ + l) * H_;
#pragma unroll
    for (int nbi = 0; nbi < 4; ++nbi) {
      const int n = (nb0 + nbi) * 16 + l15;
      const float bias = bhrow[n];
#pragma unroll
      for (int mt = 0; mt < 4; ++mt) {
        const int rbase = mt * 16 + quad * 4;
#pragma unroll
        for (int i = 0; i < 4; ++i) {
          const float z = OMEGA_ * (acc[mt][nbi][i] + bias);
          const float h = __sinf(z);
          __bf16 hi, lo; split_bf16(h, hi, lo);
          h_hi[(rbase + i) * HPAD + n] = hi;
          h_lo[(rbase + i) * HPAD + n] = lo;
        }
      }
    }
    __syncthreads();
  }

  {
    const float* WO = Wout + (size_t)e * (H_ * 3);
    f32x4 acco = (f32x4){0.f, 0.f, 0.f, 0.f};
    const int arow = wave * 16 + l15;
#pragma unroll
    for (int kb = 0; kb < 8; ++kb) {
      const int k0 = kb * 32 + quad * 8;
      float bfv[8];
#pragma unroll
      for (int j = 0; j < 8; ++j)
        bfv[j] = (l15 < 3) ? WO[(size_t)(k0 + j) * 3 + l15] : 0.0f;
      bf16x8 ah = *reinterpret_cast<const bf16x8*>(&h_hi[arow * HPAD + k0]);
      bf16x8 al = *reinterpret_cast<const bf16x8*>(&h_lo[arow * HPAD + k0]);
      bf16x8 bhf, blf;
#pragma unroll
      for (int j = 0; j < 8; ++j) {
        __bf16 hi, lo; split_bf16(bfv[j], hi, lo);
        bhf[j] = hi; blf[j] = lo;
      }
      acco = __builtin_amdgcn_mfma_f32_16x16x32_bf16(al, bhf, acco, 0, 0, 0);
      acco = __builtin_amdgcn_mfma_f32_16x16x32_bf16(ah, blf, acco, 0, 0, 0);
      acco = __builtin_amdgcn_mfma_f32_16x16x32_bf16(ah, bhf, acco, 0, 0, 0);
    }
    if (l15 < 3) {
      const float bo = bout[e * 3 + l15];
      const int rb = wave * 16 + quad * 4;
#pragma unroll
      for (int i = 0; i < 4; ++i) {
        const int m = rb + i;
        const float val = gate_s[m] * (acco[i] + bo);
        atomicAdd(&out[(size_t)(m0 + m) * 3 + l15], val);
      }
    }
  }
}

extern "C" void kernel_launch(void* const* d_in, const int* in_sizes, int n_in,
                              void* d_out, int out_size, void* d_ws, size_t ws_size,
                              hipStream_t stream) {
  const float* x     = (const float*)d_in[0];
  const float* gateW = (const float*)d_in[1];
  const float* gateb = (const float*)d_in[2];
  const float* W0    = (const float*)d_in[3];
  const float* b0    = (const float*)d_in[4];
  const float* Wh    = (const float*)d_in[5];
  const float* bh    = (const float*)d_in[6];
  const float* Wout  = (const float*)d_in[7];
  const float* bout  = (const float*)d_in[8];
  float* out = (float*)d_out;

  hipLaunchKernelGGL(zero_out_k, dim3(N_ * 3 / 256), dim3(256), 0, stream, out);

  if (ws_size >= WS_NEEDED) {
    __bf16* Pwh_hi = (__bf16*)d_ws;
    __bf16* Pwh_lo = (__bf16*)((char*)d_ws + (size_t)PWH_ELEMS * 2);
    __bf16* Pwo_hi = (__bf16*)((char*)d_ws + 2 * (size_t)PWH_ELEMS * 2);
    __bf16* Pwo_lo = (__bf16*)((char*)d_ws + 2 * (size_t)PWH_ELEMS * 2 + (size_t)PWO_ELEMS * 2);
    hipLaunchKernelGGL(pack_wh_k,  dim3(768), dim3(256), 0, stream, Wh, Pwh_hi, Pwh_lo);
    hipLaunchKernelGGL(pack_wout_k, dim3(16), dim3(256), 0, stream, Wout, Pwo_hi, Pwo_lo);
    hipLaunchKernelGGL(moe_main_packed_k, dim3(N_ / (2 * MT), E_), dim3(256), 0, stream,
                       x, gateW, gateb, W0, b0, Pwh_hi, Pwh_lo, bh, Pwo_hi, Pwo_lo, bout, out);
  } else {
    hipLaunchKernelGGL(moe_main_direct_k, dim3(N_ / MT, E_), dim3(256), 0, stream,
                       x, gateW, gateb, W0, b0, Wh, bh, Wout, bout, out);
  }
}

// Round 18
// 292.595 us; speedup vs baseline: 1.0480x; 1.0480x over previous
//
#include <hip/hip_runtime.h>
#include <math.h>

#define E_ 8
#define H_ 256
#define N_ 65536
#define NHID_ 3
#define MT 64          // tile: N/64 = 1024 exact
#define HPAD 264       // LDS row stride (bf16 elems): row stride 528B
#define OMEGA_ 30.0f
#define REV_SCALE 4.7746482927568605f   // OMEGA/(2*pi): sin(OMEGA*z) = sin(2pi*(REV_SCALE*z))

// ws layout: Pwh_hi | Pwh_lo | Pwo_hi | Pwo_lo (lo planes used only by output layer / fallback)
#define PWH_ELEMS (E_ * NHID_ * 8 * 16 * 64 * 8)   // 1572864 bf16 = 3145728 B
#define PWO_ELEMS (E_ * 8 * 64 * 8)                // 32768 bf16 = 65536 B
#define WS_NEEDED (2 * (size_t)PWH_ELEMS * 2 + 2 * (size_t)PWO_ELEMS * 2)  // 6422528 B

typedef __attribute__((ext_vector_type(8))) __bf16 bf16x8;
typedef __attribute__((ext_vector_type(4))) float f32x4;

// RNE split (pack kernels + fallback path)
__device__ __forceinline__ void split_bf16(float v, __bf16& hi, __bf16& lo) {
  hi = (__bf16)v;
  lo = (__bf16)(v - (float)hi);
}

// hot-path: sin + RNE-bf16 + single LDS store
__device__ __forceinline__ void sin_store(float z_rev, __bf16* h_hi, int idx) {
  const float s = __builtin_amdgcn_sinf(__builtin_amdgcn_fractf(z_rev)); // sin(2*pi*z_rev)
  h_hi[idx] = (__bf16)s;   // RNE
}

// ---- zero d_out ----
__global__ void zero_out_k(float* __restrict__ out) {
  out[blockIdx.x * 256 + threadIdx.x] = 0.0f;   // grid exactly N_*3/256
}

// ---- pack Wh*REV_SCALE -> bf16 hi/lo B-fragment order (16x16x32) ----
// value(t,j) = REV_SCALE * Wh[el][kb*32+quad*8+j][nb*16+l15]
// threads = 8*3*8*16*64 = 196608 -> grid 768 x 256
__global__ void pack_wh_k(const float* __restrict__ Wh,
                          __bf16* __restrict__ Phi, __bf16* __restrict__ Plo) {
  int t = blockIdx.x * 256 + threadIdx.x;
  int lane = t & 63;
  int r = t >> 6;            // [0, 3072)
  int nb = r & 15;
  int kb = (r >> 4) & 7;
  int el = r >> 7;           // [0, 24) = e*3+l
  int n  = nb * 16 + (lane & 15);
  int k0 = kb * 32 + (lane >> 4) * 8;
  const float* src = Wh + (size_t)el * (H_ * H_);
  __bf16* dhi = Phi + (size_t)t * 8;
  __bf16* dlo = Plo + (size_t)t * 8;
#pragma unroll
  for (int j = 0; j < 8; ++j) {
    __bf16 hi, lo;
    split_bf16(src[(size_t)(k0 + j) * H_ + n] * REV_SCALE, hi, lo);
    dhi[j] = hi; dlo[j] = lo;
  }
}

// ---- pack Wout (UNscaled — final layer is linear), 16x16x32 layout ----
__global__ void pack_wout_k(const float* __restrict__ Wout,
                            __bf16* __restrict__ Phi, __bf16* __restrict__ Plo) {
  int t = blockIdx.x * 256 + threadIdx.x;   // 4096 threads -> grid 16 x 256
  int lane = t & 63;
  int kb = (t >> 6) & 7;
  int e  = t >> 9;
  int n  = lane & 15;
  int k0 = kb * 32 + (lane >> 4) * 8;
  __bf16* dhi = Phi + (size_t)t * 8;
  __bf16* dlo = Plo + (size_t)t * 8;
#pragma unroll
  for (int j = 0; j < 8; ++j) {
    float v = (n < 3) ? Wout[((size_t)e * H_ + (k0 + j)) * 3 + n] : 0.0f;
    __bf16 hi, lo;
    split_bf16(v, hi, lo);
    dhi[j] = hi; dlo[j] = lo;
  }
}

// ---- fused MoE-SIREN, PACKED path, MT=64, single-MFMA hidden layers ----
// R18 = exact revert to R16 (best verified: steady 231us). R17's intra-wave
// fusion regressed (262us): LDS 68KB halved occupancy -> ~60us latency
// exposure outweighed ~15us VALU savings. With cross-wave drift (R14/16),
// stagger (R15), and intra-wave fusion (R17) all refuted, dur = MFMA work
// (99us, = m06 ceiling while busy) + VALU work (120us, irreducible sin/cvt/
// store) + ~12us barriers is the structural floor of this phase layout.
__global__ __launch_bounds__(256, 4) void moe_main_packed_k(
    const float* __restrict__ x,
    const float* __restrict__ gate_W,
    const float* __restrict__ gate_b,
    const float* __restrict__ W0,
    const float* __restrict__ b0,
    const __bf16* __restrict__ Pwh_hi,
    const __bf16* __restrict__ Pwh_lo,
    const float* __restrict__ bh,
    const __bf16* __restrict__ Pwo_hi,
    const __bf16* __restrict__ Pwo_lo,
    const float* __restrict__ bout,
    float* __restrict__ out)
{
  __shared__ alignas(16) __bf16 h_hi[MT * HPAD];   // 33792 B
  __shared__ float gate_s[MT];                     // total ~34 KB -> 4 blocks/CU

  const int e    = blockIdx.y;
  const int m0   = blockIdx.x * MT;
  const int tid  = threadIdx.x;
  const int wave = tid >> 6;
  const int lane = tid & 63;
  const int l15  = lane & 15;
  const int quad = lane >> 4;

  // gate for this expert, one row per thread (fp32, matches jax softmax)
  if (tid < MT) {
    const int mg = m0 + tid;
    const float x0 = x[mg * 2 + 0];
    const float x1 = x[mg * 2 + 1];
    float lg[E_];
    float mx = -1e30f;
#pragma unroll
    for (int k = 0; k < E_; ++k) {
      lg[k] = x0 * gate_W[k] + x1 * gate_W[E_ + k] + gate_b[k];
      mx = fmaxf(mx, lg[k]);
    }
    float s = 0.0f;
#pragma unroll
    for (int k = 0; k < E_; ++k) s += __expf(lg[k] - mx);
    gate_s[tid] = __expf(lg[e] - mx) / s;
  }

  // first sine layer fp32, omega/2pi folded; thread tid owns column n=tid, all 64 rows
  {
    const float w0a = W0[(e * 2 + 0) * H_ + tid] * REV_SCALE;
    const float w1a = W0[(e * 2 + 1) * H_ + tid] * REV_SCALE;
    const float bb  = b0[e * H_ + tid] * REV_SCALE;
    for (int m = 0; m < MT; ++m) {
      const float x0 = x[(m0 + m) * 2 + 0];
      const float x1 = x[(m0 + m) * 2 + 1];
      const float z_rev = fmaf(x1, w1a, fmaf(x0, w0a, bb));
      sin_store(z_rev, h_hi, m * HPAD + tid);
    }
  }
  __syncthreads();

  const int nb0 = wave * 4;
  const size_t fragoff = (size_t)(nb0 * 64 + lane) * 8;   // wave-invariant frag offset

#pragma unroll 1
  for (int l = 0; l < NHID_; ++l) {
    const size_t lbase = (size_t)(e * NHID_ + l) * (8 * 16 * 64 * 8);
    const __bf16* pBh = Pwh_hi + lbase + fragoff;
    const float* bhrow = bh + (size_t)(e * NHID_ + l) * H_;

    // bias folded into acc init (C/D col = lane-only -> one bias per nbi, all 16 regs)
    float bias_rev[4];
#pragma unroll
    for (int nbi = 0; nbi < 4; ++nbi)
      bias_rev[nbi] = bhrow[(nb0 + nbi) * 16 + l15] * REV_SCALE;

    f32x4 acc[4][4];
#pragma unroll
    for (int mt = 0; mt < 4; ++mt)
#pragma unroll
      for (int nbi = 0; nbi < 4; ++nbi)
        acc[mt][nbi] = (f32x4){bias_rev[nbi], bias_rev[nbi], bias_rev[nbi], bias_rev[nbi]};

#pragma unroll 1          // ONE kb in flight: VGPR discipline
    for (int kb = 0; kb < 8; ++kb) {
      bf16x8 bhf[4];
#pragma unroll
      for (int nbi = 0; nbi < 4; ++nbi)
        bhf[nbi] = *reinterpret_cast<const bf16x8*>(pBh + nbi * 512);
      pBh += 16 * 64 * 8;   // 8192 elems per kb
      const int k0 = kb * 32 + quad * 8;
      bf16x8 ah[4];
#pragma unroll
      for (int mt = 0; mt < 4; ++mt)
        ah[mt] = *reinterpret_cast<const bf16x8*>(&h_hi[(mt * 16 + l15) * HPAD + k0]);
#pragma unroll
      for (int mt = 0; mt < 4; ++mt)
#pragma unroll
        for (int nbi = 0; nbi < 4; ++nbi)
          acc[mt][nbi] = __builtin_amdgcn_mfma_f32_16x16x32_bf16(
              ah[mt], bhf[nbi], acc[mt][nbi], 0, 0, 0);
    }
    __syncthreads();

#pragma unroll
    for (int nbi = 0; nbi < 4; ++nbi) {
      const int n = (nb0 + nbi) * 16 + l15;
#pragma unroll
      for (int mt = 0; mt < 4; ++mt) {
        const int rbase = mt * 16 + quad * 4;
#pragma unroll
        for (int i = 0; i < 4; ++i)
          sin_store(acc[mt][nbi][i], h_hi, (rbase + i) * HPAD + n);
      }
    }
    __syncthreads();
  }

  // output layer (linear): 2-term kept (only 16 MFMAs/wave — free accuracy)
  {
    const __bf16* pOh = Pwo_hi + (size_t)e * (8 * 64 * 8) + (size_t)lane * 8;
    const __bf16* pOl = Pwo_lo + (size_t)e * (8 * 64 * 8) + (size_t)lane * 8;
    f32x4 acco = (f32x4){0.f, 0.f, 0.f, 0.f};
    const int arow = wave * 16 + l15;
#pragma unroll 1
    for (int kb = 0; kb < 8; ++kb) {
      bf16x8 bhf = *reinterpret_cast<const bf16x8*>(pOh);
      bf16x8 blf = *reinterpret_cast<const bf16x8*>(pOl);
      pOh += 512; pOl += 512;
      const int k0 = kb * 32 + quad * 8;
      bf16x8 ah = *reinterpret_cast<const bf16x8*>(&h_hi[arow * HPAD + k0]);
      acco = __builtin_amdgcn_mfma_f32_16x16x32_bf16(ah, blf, acco, 0, 0, 0);
      acco = __builtin_amdgcn_mfma_f32_16x16x32_bf16(ah, bhf, acco, 0, 0, 0);
    }
    if (l15 < 3) {
      const float bo = bout[e * 3 + l15];
      const int rb = wave * 16 + quad * 4;
#pragma unroll
      for (int i = 0; i < 4; ++i) {
        const int m = rb + i;
        const float val = gate_s[m] * (acco[i] + bo);
        atomicAdd(&out[(size_t)(m0 + m) * 3 + l15], val);
      }
    }
  }
}

// ---- fallback: direct fp32-weight path (HW-verified round 3, MT=64, 3-term) ----
__global__ __launch_bounds__(256) void moe_main_direct_k(
    const float* __restrict__ x,
    const float* __restrict__ gate_W,
    const float* __restrict__ gate_b,
    const float* __restrict__ W0,
    const float* __restrict__ b0,
    const float* __restrict__ Wh,
    const float* __restrict__ bh,
    const float* __restrict__ Wout,
    const float* __restrict__ bout,
    float* __restrict__ out)
{
  __shared__ alignas(16) __bf16 h_hi[MT * HPAD];
  __shared__ alignas(16) __bf16 h_lo[MT * HPAD];
  __shared__ float gate_s[MT];

  const int e    = blockIdx.y;
  const int m0   = blockIdx.x * MT;
  const int tid  = threadIdx.x;
  const int wave = tid >> 6;
  const int lane = tid & 63;
  const int l15  = lane & 15;
  const int quad = lane >> 4;

  if (tid < MT) {
    const int mg = m0 + tid;
    const float x0 = x[mg * 2 + 0];
    const float x1 = x[mg * 2 + 1];
    float lg[E_];
    float mx = -1e30f;
#pragma unroll
    for (int k = 0; k < E_; ++k) {
      lg[k] = x0 * gate_W[k] + x1 * gate_W[E_ + k] + gate_b[k];
      mx = fmaxf(mx, lg[k]);
    }
    float s = 0.0f;
#pragma unroll
    for (int k = 0; k < E_; ++k) s += __expf(lg[k] - mx);
    gate_s[tid] = __expf(lg[e] - mx) / s;
  }
  {
    const float w0a = W0[(e * 2 + 0) * H_ + tid];
    const float w1a = W0[(e * 2 + 1) * H_ + tid];
    const float bb  = b0[e * H_ + tid];
    for (int m = 0; m < MT; ++m) {
      const float x0 = x[(m0 + m) * 2 + 0];
      const float x1 = x[(m0 + m) * 2 + 1];
      const float z = OMEGA_ * fmaf(x1, w1a, fmaf(x0, w0a, bb));
      const float h = __sinf(z);
      __bf16 hi, lo; split_bf16(h, hi, lo);
      h_hi[m * HPAD + tid] = hi;
      h_lo[m * HPAD + tid] = lo;
    }
  }
  __syncthreads();

  const int nb0 = wave * 4;
#pragma unroll 1
  for (int l = 0; l < NHID_; ++l) {
    const float* WB = Wh + (size_t)(e * NHID_ + l) * (H_ * H_);
    f32x4 acc[4][4];
#pragma unroll
    for (int mt = 0; mt < 4; ++mt)
#pragma unroll
      for (int nbi = 0; nbi < 4; ++nbi)
        acc[mt][nbi] = (f32x4){0.f, 0.f, 0.f, 0.f};

#pragma unroll 2
    for (int kb = 0; kb < 8; ++kb) {
      const int k0 = kb * 32 + quad * 8;
      float bfv[4][8];
#pragma unroll
      for (int nbi = 0; nbi < 4; ++nbi) {
        const float* p = WB + (size_t)k0 * H_ + (nb0 + nbi) * 16 + l15;
#pragma unroll
        for (int j = 0; j < 8; ++j) bfv[nbi][j] = p[(size_t)j * H_];
      }
      bf16x8 ah[4], al[4];
#pragma unroll
      for (int mt = 0; mt < 4; ++mt) {
        ah[mt] = *reinterpret_cast<const bf16x8*>(&h_hi[(mt * 16 + l15) * HPAD + k0]);
        al[mt] = *reinterpret_cast<const bf16x8*>(&h_lo[(mt * 16 + l15) * HPAD + k0]);
      }
      bf16x8 bhf[4], blf[4];
#pragma unroll
      for (int nbi = 0; nbi < 4; ++nbi)
#pragma unroll
        for (int j = 0; j < 8; ++j) {
          __bf16 hi, lo; split_bf16(bfv[nbi][j], hi, lo);
          bhf[nbi][j] = hi; blf[nbi][j] = lo;
        }
#pragma unroll
      for (int mt = 0; mt < 4; ++mt)
#pragma unroll
        for (int nbi = 0; nbi < 4; ++nbi) {
          f32x4 a = acc[mt][nbi];
          a = __builtin_amdgcn_mfma_f32_16x16x32_bf16(al[mt], bhf[nbi], a, 0, 0, 0);
          a = __builtin_amdgcn_mfma_f32_16x16x32_bf16(ah[mt], blf[nbi], a, 0, 0, 0);
          a = __builtin_amdgcn_mfma_f32_16x16x32_bf16(ah[mt], bhf[nbi], a, 0, 0, 0);
          acc[mt][nbi] = a;
        }
    }
    __syncthreads();

    const float* bhrow = bh + (size_t)(e * NHID_ + l) * H_;
#pragma unroll
    for (int nbi = 0; nbi < 4; ++nbi) {
      const int n = (nb0 + nbi) * 16 + l15;
      const float bias = bhrow[n];
#pragma unroll
      for (int mt = 0; mt < 4; ++mt) {
        const int rbase = mt * 16 + quad * 4;
#pragma unroll
        for (int i = 0; i < 4; ++i) {
          const float z = OMEGA_ * (acc[mt][nbi][i] + bias);
          const float h = __sinf(z);
          __bf16 hi, lo; split_bf16(h, hi, lo);
          h_hi[(rbase + i) * HPAD + n] = hi;
          h_lo[(rbase + i) * HPAD + n] = lo;
        }
      }
    }
    __syncthreads();
  }

  {
    const float* WO = Wout + (size_t)e * (H_ * 3);
    f32x4 acco = (f32x4){0.f, 0.f, 0.f, 0.f};
    const int arow = wave * 16 + l15;
#pragma unroll
    for (int kb = 0; kb < 8; ++kb) {
      const int k0 = kb * 32 + quad * 8;
      float bfv[8];
#pragma unroll
      for (int j = 0; j < 8; ++j)
        bfv[j] = (l15 < 3) ? WO[(size_t)(k0 + j) * 3 + l15] : 0.0f;
      bf16x8 ah = *reinterpret_cast<const bf16x8*>(&h_hi[arow * HPAD + k0]);
      bf16x8 al = *reinterpret_cast<const bf16x8*>(&h_lo[arow * HPAD + k0]);
      bf16x8 bhf, blf;
#pragma unroll
      for (int j = 0; j < 8; ++j) {
        __bf16 hi, lo; split_bf16(bfv[j], hi, lo);
        bhf[j] = hi; blf[j] = lo;
      }
      acco = __builtin_amdgcn_mfma_f32_16x16x32_bf16(al, bhf, acco, 0, 0, 0);
      acco = __builtin_amdgcn_mfma_f32_16x16x32_bf16(ah, blf, acco, 0, 0, 0);
      acco = __builtin_amdgcn_mfma_f32_16x16x32_bf16(ah, bhf, acco, 0, 0, 0);
    }
    if (l15 < 3) {
      const float bo = bout[e * 3 + l15];
      const int rb = wave * 16 + quad * 4;
#pragma unroll
      for (int i = 0; i < 4; ++i) {
        const int m = rb + i;
        const float val = gate_s[m] * (acco[i] + bo);
        atomicAdd(&out[(size_t)(m0 + m) * 3 + l15], val);
      }
    }
  }
}

extern "C" void kernel_launch(void* const* d_in, const int* in_sizes, int n_in,
                              void* d_out, int out_size, void* d_ws, size_t ws_size,
                              hipStream_t stream) {
  const float* x     = (const float*)d_in[0];
  const float* gateW = (const float*)d_in[1];
  const float* gateb = (const float*)d_in[2];
  const float* W0    = (const float*)d_in[3];
  const float* b0    = (const float*)d_in[4];
  const float* Wh    = (const float*)d_in[5];
  const float* bh    = (const float*)d_in[6];
  const float* Wout  = (const float*)d_in[7];
  const float* bout  = (const float*)d_in[8];
  float* out = (float*)d_out;

  hipLaunchKernelGGL(zero_out_k, dim3(N_ * 3 / 256), dim3(256), 0, stream, out);

  if (ws_size >= WS_NEEDED) {
    __bf16* Pwh_hi = (__bf16*)d_ws;
    __bf16* Pwh_lo = (__bf16*)((char*)d_ws + (size_t)PWH_ELEMS * 2);
    __bf16* Pwo_hi = (__bf16*)((char*)d_ws + 2 * (size_t)PWH_ELEMS * 2);
    __bf16* Pwo_lo = (__bf16*)((char*)d_ws + 2 * (size_t)PWH_ELEMS * 2 + (size_t)PWO_ELEMS * 2);
    hipLaunchKernelGGL(pack_wh_k,  dim3(768), dim3(256), 0, stream, Wh, Pwh_hi, Pwh_lo);
    hipLaunchKernelGGL(pack_wout_k, dim3(16), dim3(256), 0, stream, Wout, Pwo_hi, Pwo_lo);
    hipLaunchKernelGGL(moe_main_packed_k, dim3(N_ / MT, E_), dim3(256), 0, stream,
                       x, gateW, gateb, W0, b0, Pwh_hi, Pwh_lo, bh, Pwo_hi, Pwo_lo, bout, out);
  } else {
    hipLaunchKernelGGL(moe_main_direct_k, dim3(N_ / MT, E_), dim3(256), 0, stream,
                       x, gateW, gateb, W0, b0, Wh, bh, Wout, bout, out);
  }
}